// Round 4
// baseline (2364.188 us; speedup 1.0000x reference)
//
#include <hip/hip_runtime.h>

typedef _Float16 f16;
typedef _Float16 h2 __attribute__((ext_vector_type(2)));
typedef _Float16 f16x8 __attribute__((ext_vector_type(8)));
typedef float f32x4 __attribute__((ext_vector_type(4)));
typedef unsigned int u32;

#define TB  256
#define TTT 2000
#define INW 42
#define HV  24
#define HN  48
#define HD  96
#define NTH 640

// combined activation ring buffer, f16 cols per slot:
// [0,24) tmp | [24,48) vadh | [48,90) x | [90,96) 0 | [96,144) noih | [144,160) 0 | [160,256) denh
#define C_TMP 0
#define C_VAD 24
#define C_X   48
#define C_NOI 96
#define C_DEN 160
#define ACTW  256

__device__ __forceinline__ float fsigm(float v) {
    return __builtin_amdgcn_rcpf(1.0f + __builtin_amdgcn_exp2f(-1.44269504089f * v));
}
__device__ __forceinline__ float ftanh(float v) {
    float e = __builtin_amdgcn_exp2f(2.88539008178f * v);
    return 1.0f - 2.0f * __builtin_amdgcn_rcpf(e + 1.0f);
}
__device__ __forceinline__ float dot2f(u32 a, u32 w, float c) {
#if __has_builtin(__builtin_amdgcn_fdot2)
    return __builtin_amdgcn_fdot2(__builtin_bit_cast(h2, a), __builtin_bit_cast(h2, w), c, false);
#else
    h2 av = __builtin_bit_cast(h2, a), wv = __builtin_bit_cast(h2, w);
    return c + (float)av[0] * (float)wv[0] + (float)av[1] * (float)wv[1];
#endif
}
__device__ __forceinline__ u32 packw(float a, float b) {
    h2 v; v[0] = (f16)a; v[1] = (f16)b;
    return __builtin_bit_cast(u32, v);
}
template<int CTRL>
__device__ __forceinline__ float dpp_add(float x) {
    int y = __builtin_amdgcn_mov_dpp(__builtin_bit_cast(int, x), CTRL, 0xF, 0xF, true);
    return x + __builtin_bit_cast(float, y);
}

// raw barrier: flush LDS ops, do NOT drain vmcnt (keeps x prefetch + global stores in flight)
#define SYNCB() asm volatile("s_waitcnt lgkmcnt(0)\n\ts_barrier" ::: "memory")

#define MFMA16(A, B, C) __builtin_amdgcn_mfma_f32_16x16x32_f16((A), (B), (C), 0, 0, 0)

// vad-wave dot2 macros (input-side rr,zz,an / hidden-side rr,zz,hn)
#define ACCI(AV, W, IDX) do { u32 _a = (AV); \
    rr = dot2f(_a, W[0][IDX], rr); zz = dot2f(_a, W[1][IDX], zz); an = dot2f(_a, W[2][IDX], an); } while (0)
#define ACCH(AV, W, IDX) do { u32 _a = (AV); \
    rr = dot2f(_a, W[0][IDX], rr); zz = dot2f(_a, W[1][IDX], zz); hn = dot2f(_a, W[2][IDX], hn); } while (0)
#define RED4_1() do { \
    rr = dpp_add<0xB1>(rr); zz = dpp_add<0xB1>(zz); \
    an = dpp_add<0xB1>(an); hn = dpp_add<0xB1>(hn); } while (0)

template<int N> struct IC { static constexpr int val = N; };

__device__ __forceinline__ f16x8 ldsb(const f16* p) {
    uint4 t = *(const uint4*)p;
    return __builtin_bit_cast(f16x8, t);
}

__global__ __launch_bounds__(NTH, 1) void rnnoise_kernel(
    const float* __restrict__ gx,
    const float* __restrict__ in_w,      const float* __restrict__ in_b,
    const float* __restrict__ vad_wih,   const float* __restrict__ vad_whh,
    const float* __restrict__ vad_bih,   const float* __restrict__ vad_bhh,
    const float* __restrict__ vad_out_w, const float* __restrict__ vad_out_b,
    const float* __restrict__ noise_wih, const float* __restrict__ noise_whh,
    const float* __restrict__ noise_bih, const float* __restrict__ noise_bhh,
    const float* __restrict__ den_wih,   const float* __restrict__ den_whh,
    const float* __restrict__ den_bih,   const float* __restrict__ den_bhh,
    const float* __restrict__ out_w,     const float* __restrict__ out_b,
    float* __restrict__ gains, float* __restrict__ vout)
{
    __shared__ __align__(16) f16 act[4][ACTW];   // 2 KB, slot = timestep & 3

    const int tid  = threadIdx.x;
    const int wid  = tid >> 6;
    const int lane = tid & 63;
    const int b    = blockIdx.x;
    const int g4   = lane >> 4;     // k-chunk group / D row-group
    const int rrow = lane & 15;     // A row within 16-row tile

    if (tid < 512) ((u32*)act)[tid] = 0u;

    const int role = (wid == 9) ? 2 : ((wid == 4 || wid == 5 || wid == 8) ? 1 : 0);

    if (role == 0) {
        // ================== DEN (MFMA): t = k-3 at tick k; OUT (waves 0,1): t = k-4 ==================
        const int dwi = (wid < 4) ? wid : (wid - 2);     // 0..5 -> units 16*dwi + rrow
        const int u_a = 16 * dwi + rrow;                 // A row unit
        // A k-layout (K=224): [0,24) vadh | [24,66) x | [66,72) 0 | [72,120) noih | [120,128) 0 | [128,224) denh
        f16x8 ag[3][7];
        #pragma unroll
        for (int g = 0; g < 3; ++g) {
            const float* wi = den_wih + (g * HD + u_a) * 114;
            const float* wh = den_whh + (g * HD + u_a) * HD;
            #pragma unroll
            for (int kt = 0; kt < 7; ++kt) {
                #pragma unroll
                for (int j = 0; j < 8; ++j) {
                    int k = (kt < 4) ? (32 * kt + 8 * g4 + j) : (128 + 32 * (kt - 4) + 8 * g4 + j);
                    float w = 0.f;
                    if (k < 24)        w = wi[k];            // vadh cols
                    else if (k < 66)   w = wi[72 + (k - 24)];// x cols
                    else if (k < 72)   w = 0.f;
                    else if (k < 120)  w = wi[24 + (k - 72)];// noih cols
                    else if (k < 128)  w = 0.f;
                    else               w = wh[k - 128];      // denh (hh)
                    ag[g][kt][j] = (f16)w;
                }
            }
        }
        // out-projection A frags on waves 0,1 (rows o = 16*dwi + rrow, K = 96 denh)
        f16x8 ao0 = {}, ao1 = {}, ao2 = {};
        if (dwi < 2) {
            int o = 16 * dwi + rrow;
            #pragma unroll
            for (int j = 0; j < 8; ++j) {
                ao0[j] = (f16)((o < 22) ? out_w[o * HD +  0 + 8 * g4 + j] : 0.f);
                ao1[j] = (f16)((o < 22) ? out_w[o * HD + 32 + 8 * g4 + j] : 0.f);
                ao2[j] = (f16)((o < 22) ? out_w[o * HD + 64 + 8 * g4 + j] : 0.f);
            }
        }
        float bdr[4], bdz[4], bdni[4], bdnh[4], bog[4];
        #pragma unroll
        for (int i = 0; i < 4; ++i) {
            int u = 16 * dwi + 4 * g4 + i;
            bdr[i]  = den_bih[u]        + den_bhh[u];
            bdz[i]  = den_bih[HD + u]   + den_bhh[HD + u];
            bdni[i] = den_bih[2*HD + u];
            bdnh[i] = den_bhh[2*HD + u];
            int o = 16 * dwi + 4 * g4 + i;
            bog[i] = (dwi < 2 && o < 22) ? out_b[o] : 0.f;
        }
        float hprev[4] = {0.f, 0.f, 0.f, 0.f};
        __syncthreads();

        auto step = [&](auto PC, int k) {
            constexpr int P  = decltype(PC)::val;
            constexpr int SI = (P + 1) & 3;      // slot of t = k-3 (inputs + denh write)
            // denh(k-4) B frags from slot P (zeros before first write)
            f16x8 bh0 = ldsb(&act[P][C_DEN +  0 + 8 * g4]);
            f16x8 bh1 = ldsb(&act[P][C_DEN + 32 + 8 * g4]);
            f16x8 bh2 = ldsb(&act[P][C_DEN + 64 + 8 * g4]);
            if (k >= 3 && k <= TTT + 2) {
                f16x8 b0 = ldsb(&act[SI][24 +  0 + 8 * g4]);
                f16x8 b1 = ldsb(&act[SI][24 + 32 + 8 * g4]);
                f16x8 b2 = ldsb(&act[SI][24 + 64 + 8 * g4]);
                f16x8 b3 = ldsb(&act[SI][24 + 96 + 8 * g4]);
                f32x4 aR = {0,0,0,0}, aZ = {0,0,0,0}, aNi = {0,0,0,0}, aNh = {0,0,0,0};
                aR = MFMA16(ag[0][0], b0, aR); aZ = MFMA16(ag[1][0], b0, aZ); aNi = MFMA16(ag[2][0], b0, aNi);
                aR = MFMA16(ag[0][1], b1, aR); aZ = MFMA16(ag[1][1], b1, aZ); aNi = MFMA16(ag[2][1], b1, aNi);
                aR = MFMA16(ag[0][2], b2, aR); aZ = MFMA16(ag[1][2], b2, aZ); aNi = MFMA16(ag[2][2], b2, aNi);
                aR = MFMA16(ag[0][3], b3, aR); aZ = MFMA16(ag[1][3], b3, aZ); aNi = MFMA16(ag[2][3], b3, aNi);
                aR = MFMA16(ag[0][4], bh0, aR); aZ = MFMA16(ag[1][4], bh0, aZ); aNh = MFMA16(ag[2][4], bh0, aNh);
                aR = MFMA16(ag[0][5], bh1, aR); aZ = MFMA16(ag[1][5], bh1, aZ); aNh = MFMA16(ag[2][5], bh1, aNh);
                aR = MFMA16(ag[0][6], bh2, aR); aZ = MFMA16(ag[1][6], bh2, aZ); aNh = MFMA16(ag[2][6], bh2, aNh);
                #pragma unroll
                for (int i = 0; i < 4; ++i) {
                    float r = fsigm(aR[i] + bdr[i]);
                    float z = fsigm(aZ[i] + bdz[i]);
                    float n = ftanh(aNi[i] + bdni[i] + r * (aNh[i] + bdnh[i]));
                    hprev[i] = z * (hprev[i] - n) + n;
                }
                if ((lane & 15) == 0) {
                    h2 p0, p1;
                    p0[0] = (f16)hprev[0]; p0[1] = (f16)hprev[1];
                    p1[0] = (f16)hprev[2]; p1[1] = (f16)hprev[3];
                    uint2 w; w.x = __builtin_bit_cast(u32, p0); w.y = __builtin_bit_cast(u32, p1);
                    *(uint2*)&act[SI][C_DEN + 16 * dwi + 4 * g4] = w;
                }
            }
            if (dwi < 2 && k >= 4) {   // gains(t = k-4) over denh(k-4) = bh frags
                f32x4 aO = {0,0,0,0};
                aO = MFMA16(ao0, bh0, aO);
                aO = MFMA16(ao1, bh1, aO);
                aO = MFMA16(ao2, bh2, aO);
                if ((lane & 15) == 0) {
                    #pragma unroll
                    for (int i = 0; i < 4; ++i) {
                        int o = 16 * dwi + 4 * g4 + i;
                        if (o < 22)
                            gains[((size_t)b * TTT + (k - 4)) * 22 + o] = fsigm(aO[i] + bog[i]);
                    }
                }
            }
            SYNCB();
        };
        #pragma clang loop unroll(disable)
        for (int k0 = 0; k0 < TTT + 4; k0 += 4) {
            step(IC<0>{}, k0); step(IC<1>{}, k0+1); step(IC<2>{}, k0+2); step(IC<3>{}, k0+3);
        }

    } else if (role == 1) {
        // ================== NOISE (MFMA): t = k-2 at tick k ==================
        const int nwi = (wid == 4) ? 0 : ((wid == 5) ? 1 : 2);   // units 16*nwi + rrow
        const int u_a = 16 * nwi + rrow;
        // A k-layout (K=160): [0,90) wih (tmp|vadh|x) | [90,96) 0 | [96,144) whh (noih) | [144,160) 0
        f16x8 ag[3][5];
        #pragma unroll
        for (int g = 0; g < 3; ++g) {
            const float* wi = noise_wih + (g * HN + u_a) * 90;
            const float* wh = noise_whh + (g * HN + u_a) * HN;
            #pragma unroll
            for (int kt = 0; kt < 5; ++kt) {
                #pragma unroll
                for (int j = 0; j < 8; ++j) {
                    int k = (kt < 3) ? (32 * kt + 8 * g4 + j) : (96 + 32 * (kt - 3) + 8 * g4 + j);
                    float w = 0.f;
                    if (k < 90)       w = wi[k];
                    else if (k < 96)  w = 0.f;
                    else if (k < 144) w = wh[k - 96];
                    else              w = 0.f;
                    ag[g][kt][j] = (f16)w;
                }
            }
        }
        float bnr[4], bnz[4], bnni[4], bnnh[4];
        #pragma unroll
        for (int i = 0; i < 4; ++i) {
            int u = 16 * nwi + 4 * g4 + i;
            bnr[i]  = noise_bih[u]        + noise_bhh[u];
            bnz[i]  = noise_bih[HN + u]   + noise_bhh[HN + u];
            bnni[i] = noise_bih[2*HN + u];
            bnnh[i] = noise_bhh[2*HN + u];
        }
        float hprev[4] = {0.f, 0.f, 0.f, 0.f};
        __syncthreads();

        auto step = [&](auto PC, int k) {
            constexpr int P   = decltype(PC)::val;
            constexpr int SI2 = (P + 2) & 3;     // slot of t = k-2 (inputs + noih write)
            constexpr int SH  = (P + 1) & 3;     // slot of noih(k-3)
            if (k >= 2 && k <= TTT + 1) {
                f16x8 b0  = ldsb(&act[SI2][ 0 + 8 * g4]);
                f16x8 b1  = ldsb(&act[SI2][32 + 8 * g4]);
                f16x8 b2  = ldsb(&act[SI2][64 + 8 * g4]);
                f16x8 bh0 = ldsb(&act[SH][C_NOI +  0 + 8 * g4]);
                f16x8 bh1 = ldsb(&act[SH][C_NOI + 32 + 8 * g4]);
                f32x4 aR = {0,0,0,0}, aZ = {0,0,0,0}, aNi = {0,0,0,0}, aNh = {0,0,0,0};
                aR = MFMA16(ag[0][0], b0, aR); aZ = MFMA16(ag[1][0], b0, aZ); aNi = MFMA16(ag[2][0], b0, aNi);
                aR = MFMA16(ag[0][1], b1, aR); aZ = MFMA16(ag[1][1], b1, aZ); aNi = MFMA16(ag[2][1], b1, aNi);
                aR = MFMA16(ag[0][2], b2, aR); aZ = MFMA16(ag[1][2], b2, aZ); aNi = MFMA16(ag[2][2], b2, aNi);
                aR = MFMA16(ag[0][3], bh0, aR); aZ = MFMA16(ag[1][3], bh0, aZ); aNh = MFMA16(ag[2][3], bh0, aNh);
                aR = MFMA16(ag[0][4], bh1, aR); aZ = MFMA16(ag[1][4], bh1, aZ); aNh = MFMA16(ag[2][4], bh1, aNh);
                #pragma unroll
                for (int i = 0; i < 4; ++i) {
                    float r = fsigm(aR[i] + bnr[i]);
                    float z = fsigm(aZ[i] + bnz[i]);
                    float n = ftanh(aNi[i] + bnni[i] + r * (aNh[i] + bnnh[i]));
                    hprev[i] = z * (hprev[i] - n) + n;
                }
                if ((lane & 15) == 0) {
                    h2 p0, p1;
                    p0[0] = (f16)hprev[0]; p0[1] = (f16)hprev[1];
                    p1[0] = (f16)hprev[2]; p1[1] = (f16)hprev[3];
                    uint2 w; w.x = __builtin_bit_cast(u32, p0); w.y = __builtin_bit_cast(u32, p1);
                    *(uint2*)&act[SI2][C_NOI + 16 * nwi + 4 * g4] = w;
                }
            }
            SYNCB();
        };
        #pragma clang loop unroll(disable)
        for (int k0 = 0; k0 < TTT + 4; k0 += 4) {
            step(IC<0>{}, k0); step(IC<1>{}, k0+1); step(IC<2>{}, k0+2); step(IC<3>{}, k0+3);
        }

    } else {
        // ====== VAD wave (dot2): x stage + tmp(k) + vad GRU(t=k-1) + vad_out(t=k-1) ======
        const int l = lane;
        const int u = (l < 48) ? (l >> 1) : 0, q2 = l & 1;
        u32 wvi[3][6], wvh[3][6], wtm[12];
        float bvr = 0, bvz = 0, bvni = 0, bvnh = 0, btm = 0, wvo_u = 0;
        if (l < 48) {
            #pragma unroll
            for (int g = 0; g < 3; ++g) {
                const float* wi = vad_wih + (g * HV + u) * HV + 12 * q2;
                const float* wh = vad_whh + (g * HV + u) * HV + 12 * q2;
                #pragma unroll
                for (int j = 0; j < 6; ++j) {
                    wvi[g][j] = packw(wi[2*j], wi[2*j+1]);
                    wvh[g][j] = packw(wh[2*j], wh[2*j+1]);
                }
            }
            #pragma unroll
            for (int j = 0; j < 12; ++j) {
                int c0 = 24 * q2 + 2 * j;
                float a = (c0     < INW) ? in_w[u * INW + c0]     : 0.f;
                float c = (c0 + 1 < INW) ? in_w[u * INW + c0 + 1] : 0.f;
                wtm[j] = packw(a, c);
            }
            bvr  = vad_bih[u]        + vad_bhh[u];
            bvz  = vad_bih[HV + u]   + vad_bhh[HV + u];
            bvni = vad_bih[2*HV + u];
            bvnh = vad_bhh[2*HV + u];
            btm  = in_b[u];
            if (q2 == 0) wvo_u = vad_out_w[u];
        }
        const float bvo = vad_out_b[0];
        float hreg = 0.f;

        float xa = 0, xb = 0, xc = 0, xd = 0;
        if (l < INW) {
            xa = gx[((size_t)b * TTT + 0) * INW + l];
            xb = gx[((size_t)b * TTT + 1) * INW + l];
            xc = gx[((size_t)b * TTT + 2) * INW + l];
            xd = gx[((size_t)b * TTT + 3) * INW + l];
        }
        __syncthreads();

        auto step = [&](auto PC, int k) {
            constexpr int P  = decltype(PC)::val;
            constexpr int ST = (P + 3) & 3;   // slot of t = k-1 (tmp read, vadh write)
            constexpr int SH = (P + 2) & 3;   // slot of vadh(k-2)
            if (k < TTT && l < INW) {         // stage x(k) into slot P
                float xv;
                if constexpr (P == 0) xv = xa; else if constexpr (P == 1) xv = xb;
                else if constexpr (P == 2) xv = xc; else xv = xd;
                act[P][C_X + l] = (f16)xv;
            }
            if (k + 4 < TTT && l < INW) {     // refill with x(k+4)
                float xv = gx[((size_t)b * TTT + (k + 4)) * INW + l];
                if constexpr (P == 0) xa = xv; else if constexpr (P == 1) xb = xv;
                else if constexpr (P == 2) xc = xv; else xd = xv;
            }
            if (k >= 1 && k <= TTT) {         // vad GRU t = k-1
                float rr = 0, zz = 0, an = 0, hn = 0;
                if (l < 48) {
                    const uint2* tp = (const uint2*)&act[ST][C_TMP + 12 * q2];
                    const uint2* hp = (const uint2*)&act[SH][C_VAD + 12 * q2];
                    #pragma unroll
                    for (int v = 0; v < 3; ++v) {
                        uint2 a = tp[v]; ACCI(a.x, wvi, 2*v); ACCI(a.y, wvi, 2*v+1);
                        uint2 h = hp[v]; ACCH(h.x, wvh, 2*v); ACCH(h.y, wvh, 2*v+1);
                    }
                    RED4_1();
                    if (q2 == 0) {
                        float r = fsigm(rr + bvr);
                        float z = fsigm(zz + bvz);
                        float n = ftanh(an + bvni + r * (hn + bvnh));
                        hreg = z * (hreg - n) + n;
                        act[ST][C_VAD + u] = (f16)hreg;
                    }
                }
                float val = (l < 48 && q2 == 0) ? (wvo_u * hreg) : 0.f;
                val = dpp_add<0xB1>(val); val = dpp_add<0x4E>(val);
                val += __shfl_xor(val, 4); val += __shfl_xor(val, 8);
                val += __shfl_xor(val, 16); val += __shfl_xor(val, 32);
                if (l == 0) vout[(size_t)b * TTT + (k - 1)] = fsigm(val + bvo);
            }
            if (k < TTT && l < 48) {          // tmp(k) from x(k) staged this tick (intra-wave dep)
                float acc = 0;
                const uint4* xp = (const uint4*)&act[P][C_X + 24 * q2];
                #pragma unroll
                for (int v = 0; v < 3; ++v) {
                    uint4 a = xp[v];
                    acc = dot2f(a.x, wtm[4*v+0], acc); acc = dot2f(a.y, wtm[4*v+1], acc);
                    acc = dot2f(a.z, wtm[4*v+2], acc); acc = dot2f(a.w, wtm[4*v+3], acc);
                }
                acc = dpp_add<0xB1>(acc);
                if (q2 == 0) act[P][C_TMP + u] = (f16)ftanh(acc + btm);
            }
            SYNCB();
        };
        #pragma clang loop unroll(disable)
        for (int k0 = 0; k0 < TTT + 4; k0 += 4) {
            step(IC<0>{}, k0); step(IC<1>{}, k0+1); step(IC<2>{}, k0+2); step(IC<3>{}, k0+3);
        }
    }
}

extern "C" void kernel_launch(void* const* d_in, const int* in_sizes, int n_in,
                              void* d_out, int out_size, void* d_ws, size_t ws_size,
                              hipStream_t stream) {
    (void)in_sizes; (void)n_in; (void)d_ws; (void)ws_size; (void)out_size;
    const float* gx        = (const float*)d_in[0];
    const float* in_w      = (const float*)d_in[1];
    const float* in_b      = (const float*)d_in[2];
    const float* vad_wih   = (const float*)d_in[3];
    const float* vad_whh   = (const float*)d_in[4];
    const float* vad_bih   = (const float*)d_in[5];
    const float* vad_bhh   = (const float*)d_in[6];
    const float* vad_out_w = (const float*)d_in[7];
    const float* vad_out_b = (const float*)d_in[8];
    const float* noise_wih = (const float*)d_in[9];
    const float* noise_whh = (const float*)d_in[10];
    const float* noise_bih = (const float*)d_in[11];
    const float* noise_bhh = (const float*)d_in[12];
    const float* den_wih   = (const float*)d_in[13];
    const float* den_whh   = (const float*)d_in[14];
    const float* den_bih   = (const float*)d_in[15];
    const float* den_bhh   = (const float*)d_in[16];
    const float* out_w     = (const float*)d_in[17];
    const float* out_b     = (const float*)d_in[18];
    float* gains = (float*)d_out;
    float* vout  = (float*)d_out + (size_t)TB * (size_t)TTT * 22;

    rnnoise_kernel<<<dim3(TB), dim3(NTH), 0, stream>>>(
        gx, in_w, in_b, vad_wih, vad_whh, vad_bih, vad_bhh, vad_out_w, vad_out_b,
        noise_wih, noise_whh, noise_bih, noise_bhh, den_wih, den_whh, den_bih, den_bhh,
        out_w, out_b, gains, vout);
}